// Round 5
// baseline (236.026 us; speedup 1.0000x reference)
//
#include <hip/hip_runtime.h>

typedef _Float16 half8 __attribute__((ext_vector_type(8)));
typedef float floatx4 __attribute__((ext_vector_type(4)));

#define NF 40
#define NE 128
#define NP 780        // NF*(NF-1)/2
#define NPT 784       // padded to 49*16
#define NMT 49        // m-tiles of 16 pairs
#define XHB 5120      // f16 elems per batch elem (40*128)
#define NB 1024

// workspace layout (bytes); total 13,731,840 B (same footprint as R4 - proven to fit)
#define OFF_XH 0              // _Float16 x_h[1024*5120]  = 10485760 B
#define OFF_WH 10485760       // _Float16 w_h[128*128]    =    32768 B
#define OFF_IJ 10518528       // ushort  ij[784]          =     1568 B
#define OFF_PW 10520096       // _Float16 pw_h[128]       =      256 B
#define OFF_SC 10520576       // float   sc[1024*784]     =  3211264 B

// K0 flat work ranges (8 elems per chunk)
#define T0W 655360            // end of x chunks
#define T0I 657408            // end of W chunks
#define T0P 658192            // end of ij items
#define T_END 658208          // end of pw chunks

__device__ __forceinline__ half8 cvt8(const float* s) {
    float4 v0 = *(const float4*)s;
    float4 v1 = *(const float4*)(s + 4);
    half8 h;
    h[0] = (_Float16)v0.x; h[1] = (_Float16)v0.y;
    h[2] = (_Float16)v0.z; h[3] = (_Float16)v0.w;
    h[4] = (_Float16)v1.x; h[5] = (_Float16)v1.y;
    h[6] = (_Float16)v1.z; h[7] = (_Float16)v1.w;
    return h;
}

__global__ __launch_bounds__(256, 4)
void k0_prep(const float* __restrict__ xg, const float* __restrict__ wg,
             const float* __restrict__ pwg,
             _Float16* __restrict__ xh, _Float16* __restrict__ wh,
             unsigned short* __restrict__ ij, _Float16* __restrict__ pwh)
{
    int T = blockIdx.x * 256 + threadIdx.x;
    if (T < T0W) {
        *(half8*)(xh + (size_t)T * 8) = cvt8(xg + (size_t)T * 8);
    } else if (T < T0I) {
        int t = T - T0W;
        *(half8*)(wh + t * 8) = cvt8(wg + t * 8);
    } else if (T < T0P) {
        int p = T - T0I;
        unsigned short v = 0;
        if (p < NP) {
            int i = 0, rem = p;
            while (rem >= (NF - 1 - i)) { rem -= (NF - 1 - i); ++i; }
            v = (unsigned short)((i << 8) | (i + 1 + rem));
        }
        ij[p] = v;
    } else if (T < T_END) {
        int t = T - T0P;
        *(half8*)(pwh + t * 8) = cvt8(pwg + t * 8);
    }
}

// One wave = one 16-pair m-tile x 4 batch elems, software-pipelined over b.
// W fragments register-resident; no LDS in the hot loop, no barriers.
__global__ __launch_bounds__(256, 3)
void k1_scores(const _Float16* __restrict__ xh, const _Float16* __restrict__ wh,
               const unsigned short* __restrict__ ij,
               const float* __restrict__ wbg, const float* __restrict__ hg,
               float* __restrict__ sc)
{
    const int tid  = threadIdx.x;
    const int wid  = tid >> 6;
    const int lane = tid & 63;
    const int col  = lane & 15;
    const int quad = lane >> 4;
    const unsigned wave = blockIdx.x * 4u + wid;    // 0..12543
    const int mt    = wave % NMT;
    const int chunk = wave / NMT;                   // 0..255
    const int p0    = mt * 16;
    const int b0    = chunk * 4;

    // B-fragments: B[n=col][k=quad*8+j] = W[a=n*16+col][e]
    half8 bfrag[8][4];
#pragma unroll
    for (int n = 0; n < 8; ++n)
#pragma unroll
        for (int k = 0; k < 4; ++k)
            bfrag[n][k] = *(const half8*)(wh + (n * 16 + col) * NE + k * 32 + quad * 8);

    float wbr[8], hr[8];
#pragma unroll
    for (int n = 0; n < 8; ++n) {
        wbr[n] = wbg[n * 16 + col];
        hr[n]  = hg[n * 16 + col];
    }

    const int v = ij[p0 + col];                     // fixed pair per lane
    const _Float16* xi = xh + (size_t)b0 * XHB + ((v >> 8) & 255) * NE + quad * 8;
    const _Float16* xj = xh + (size_t)b0 * XHB + (v & 255) * NE + quad * 8;

    // prologue: load b0's fragments
    half8 ai[4], aj[4];
#pragma unroll
    for (int k = 0; k < 4; ++k) {
        ai[k] = *(const half8*)(xi + k * 32);
        aj[k] = *(const half8*)(xj + k * 32);
    }

#pragma unroll
    for (int bi = 0; bi < 4; ++bi) {
        half8 af[4];
#pragma unroll
        for (int k = 0; k < 4; ++k) af[k] = ai[k] * aj[k];
        if (bi < 3) {   // prefetch next b while MFMAs run
#pragma unroll
            for (int k = 0; k < 4; ++k) {
                ai[k] = *(const half8*)(xi + (size_t)(bi + 1) * XHB + k * 32);
                aj[k] = *(const half8*)(xj + (size_t)(bi + 1) * XHB + k * 32);
            }
        }

        floatx4 acc[8];
#pragma unroll
        for (int n = 0; n < 8; ++n) acc[n] = (floatx4){0.f, 0.f, 0.f, 0.f};
#pragma unroll
        for (int k = 0; k < 4; ++k)
#pragma unroll
            for (int n = 0; n < 8; ++n)
                acc[n] = __builtin_amdgcn_mfma_f32_16x16x32_f16(af[k], bfrag[n][k], acc[n], 0, 0, 0);

        // scores[p] = sum_a relu(S+wb)*h  (h_b cancels in softmax)
        float ps[4] = {0.f, 0.f, 0.f, 0.f};
#pragma unroll
        for (int n = 0; n < 8; ++n)
#pragma unroll
            for (int r = 0; r < 4; ++r)
                ps[r] += fmaxf(acc[n][r] + wbr[n], 0.f) * hr[n];
#pragma unroll
        for (int r = 0; r < 4; ++r)
#pragma unroll
            for (int off = 1; off < 16; off <<= 1)
                ps[r] += __shfl_xor(ps[r], off);
        if (col == 0) {
            float* scb = sc + (size_t)(b0 + bi) * NPT + p0 + quad * 4;
#pragma unroll
            for (int r = 0; r < 4; ++r)
                if (p0 + quad * 4 + r < NP) scb[r] = ps[r];
        }
    }
}

// Per-b tail: softmax, then out_un = sum_p exp_p * G[i,j], G = X diag(pw) X^T via MFMA.
__global__ __launch_bounds__(256, 4)
void k2_out(const _Float16* __restrict__ xh, const float* __restrict__ scg,
            const unsigned short* __restrict__ ijg, const _Float16* __restrict__ pwh,
            const float* __restrict__ pbg, float* __restrict__ out)
{
    __shared__ float G[48][49];             // 9408 B (+1 col pad)
    __shared__ float sc[NPT];               // 3136 B
    __shared__ unsigned short ij[NPT];      // 1568 B
    __shared__ float redm[4], reds[4], redo[4];

    const int tid  = threadIdx.x;
    const int wid  = tid >> 6;
    const int lane = tid & 63;
    const int b    = blockIdx.x;

    const float* scb = scg + (size_t)b * NPT;
    for (int p = tid; p < NPT; p += 256) {
        sc[p] = (p < NP) ? scb[p] : -1e30f;
        ij[p] = ijg[p];
    }
    __syncthreads();

    // softmax max
    float m = -1e30f;
    for (int p = tid; p < NP; p += 256) m = fmaxf(m, sc[p]);
#pragma unroll
    for (int off = 1; off < 64; off <<= 1) m = fmaxf(m, __shfl_xor(m, off));
    if (lane == 0) redm[wid] = m;
    __syncthreads();
    const float M = fmaxf(fmaxf(redm[0], redm[1]), fmaxf(redm[2], redm[3]));

    // exp + sum (unnormalized; 1/sum folded into final scalar)
    float s = 0.f;
    for (int p = tid; p < NP; p += 256) {
        float e = __expf(sc[p] - M);
        sc[p] = e;
        s += e;
    }
#pragma unroll
    for (int off = 1; off < 64; off <<= 1) s += __shfl_xor(s, off);
    if (lane == 0) reds[wid] = s;

    // G = X diag(pw) X^T : 3x3 padded 16x16 tiles, K=128, pw folded into B side
    const int col  = lane & 15;
    const int quad = lane >> 4;
    half8 pwf[4];
#pragma unroll
    for (int k = 0; k < 4; ++k)
        pwf[k] = *(const half8*)(pwh + k * 32 + quad * 8);
    const _Float16* xb = xh + (size_t)b * XHB;

    for (int t = wid; t < 9; t += 4) {
        const int mi = t / 3, ni = t % 3;
        const int row = mi * 16 + col;      // field i (A side)
        const int cln = ni * 16 + col;      // field j (B side)
        const bool rok = row < NF, cok = cln < NF;
        floatx4 acc = (floatx4){0.f, 0.f, 0.f, 0.f};
#pragma unroll
        for (int k = 0; k < 4; ++k) {
            half8 a = rok ? *(const half8*)(xb + row * NE + k * 32 + quad * 8) : (half8)(_Float16)0;
            half8 bb = cok ? (*(const half8*)(xb + cln * NE + k * 32 + quad * 8)) * pwf[k]
                           : (half8)(_Float16)0;
            acc = __builtin_amdgcn_mfma_f32_16x16x32_f16(a, bb, acc, 0, 0, 0);
        }
#pragma unroll
        for (int r = 0; r < 4; ++r)
            G[mi * 16 + quad * 4 + r][ni * 16 + col] = acc[r];
    }
    __syncthreads();   // sc(exp), reds, G all visible

    // out_un = sum_p exp_p * G[i,j]
    float g = 0.f;
    for (int p = tid; p < NP; p += 256) {
        int vv = ij[p];
        g += sc[p] * G[(vv >> 8) & 255][vv & 255];
    }
#pragma unroll
    for (int off = 1; off < 64; off <<= 1) g += __shfl_xor(g, off);
    if (lane == 0) redo[wid] = g;
    __syncthreads();
    if (tid == 0) {
        float S   = reds[0] + reds[1] + reds[2] + reds[3];
        float tot = redo[0] + redo[1] + redo[2] + redo[3];
        out[b] = tot / S + pbg[0];
    }
}

extern "C" void kernel_launch(void* const* d_in, const int* in_sizes, int n_in,
                              void* d_out, int out_size, void* d_ws, size_t ws_size,
                              hipStream_t stream) {
    const float* xg  = (const float*)d_in[0];  // x [1024,40,128]
    const float* wg  = (const float*)d_in[1];  // attn_w_w [128,128]
    const float* wbg = (const float*)d_in[2];  // attn_w_b [128]
    const float* hg  = (const float*)d_in[3];  // attn_h_w [1,128]
    // d_in[4] = attn_h_b : cancels in softmax
    const float* pwg = (const float*)d_in[5];  // attn_p_w [1,128]
    const float* pbg = (const float*)d_in[6];  // attn_p_b [1]

    char* ws = (char*)d_ws;
    _Float16* xh  = (_Float16*)(ws + OFF_XH);
    _Float16* wh  = (_Float16*)(ws + OFF_WH);
    unsigned short* ij = (unsigned short*)(ws + OFF_IJ);
    _Float16* pwh = (_Float16*)(ws + OFF_PW);
    float* sc     = (float*)(ws + OFF_SC);

    k0_prep<<<(T_END + 255) / 256, 256, 0, stream>>>(xg, wg, pwg, xh, wh, ij, pwh);
    k1_scores<<<NB * NMT / 16, 256, 0, stream>>>(xh, wh, ij, wbg, hg, sc); // 3136 blocks
    k2_out<<<NB, 256, 0, stream>>>(xh, sc, ij, pwh, pbg, (float*)d_out);
}

// Round 6
// 196.116 us; speedup vs baseline: 1.2035x; 1.2035x over previous
//
#include <hip/hip_runtime.h>

typedef _Float16 half8 __attribute__((ext_vector_type(8)));
typedef float floatx4 __attribute__((ext_vector_type(4)));

#define NF 40
#define NE 128
#define NP 780        // NF*(NF-1)/2
#define NPT 784       // padded to 49*16
#define NMT 49        // m-tiles of 16 pairs
#define XHB 5120      // f16 elems per batch elem (40*128)
#define NB 1024

// workspace layout (bytes); total 13,731,840 B
#define OFF_XH 0              // _Float16 x_h[1024*5120]  = 10485760 B
#define OFF_WH 10485760       // _Float16 w_h[128*128]    =    32768 B
#define OFF_IJ 10518528       // ushort  ij[784]          =     1568 B
#define OFF_PW 10520096       // _Float16 pw_h[128]       =      256 B
#define OFF_SC 10520576       // float   sc[1024*784]     =  3211264 B

// K0 flat work ranges (8 elems per chunk)
#define T0W 655360            // end of x chunks
#define T0I 657408            // end of W chunks
#define T0P 658192            // end of ij items
#define T0PW 658208           // end of pw chunks
#define T_END 758560          // end of sc-zero chunks (802816/8 = 100352)

__device__ __forceinline__ half8 cvt8(const float* s) {
    float4 v0 = *(const float4*)s;
    float4 v1 = *(const float4*)(s + 4);
    half8 h;
    h[0] = (_Float16)v0.x; h[1] = (_Float16)v0.y;
    h[2] = (_Float16)v0.z; h[3] = (_Float16)v0.w;
    h[4] = (_Float16)v1.x; h[5] = (_Float16)v1.y;
    h[6] = (_Float16)v1.z; h[7] = (_Float16)v1.w;
    return h;
}

// sum over the 16-lane DPP row (CDNA row=16): 4 rotate-add steps, pure VALU.
template<int CTRL>
__device__ __forceinline__ float ror_add(float v) {
    union { float f; int i; } a, b;
    a.f = v;
    b.i = __builtin_amdgcn_update_dpp(0, a.i, CTRL, 0xF, 0xF, true);
    return a.f + b.f;
}
__device__ __forceinline__ float row16_sum(float v) {
    v = ror_add<0x121>(v);   // row_ror:1
    v = ror_add<0x122>(v);   // row_ror:2
    v = ror_add<0x124>(v);   // row_ror:4
    v = ror_add<0x128>(v);   // row_ror:8
    return v;
}

__global__ __launch_bounds__(256, 4)
void k0_prep(const float* __restrict__ xg, const float* __restrict__ wg,
             const float* __restrict__ pwg,
             _Float16* __restrict__ xh, _Float16* __restrict__ wh,
             unsigned short* __restrict__ ij, _Float16* __restrict__ pwh,
             float* __restrict__ sc)
{
    int T = blockIdx.x * 256 + threadIdx.x;
    if (T < T0W) {
        *(half8*)(xh + (size_t)T * 8) = cvt8(xg + (size_t)T * 8);
    } else if (T < T0I) {
        int t = T - T0W;
        *(half8*)(wh + t * 8) = cvt8(wg + t * 8);
    } else if (T < T0P) {
        int p = T - T0I;
        unsigned short v = 0;
        if (p < NP) {
            int i = 0, rem = p;
            while (rem >= (NF - 1 - i)) { rem -= (NF - 1 - i); ++i; }
            v = (unsigned short)((i << 8) | (i + 1 + rem));
        }
        ij[p] = v;
    } else if (T < T0PW) {
        int t = T - T0P;
        *(half8*)(pwh + t * 8) = cvt8(pwg + t * 8);
    } else if (T < T_END) {
        int t = T - T0PW;
        *(float4*)(sc + (size_t)t * 8)     = make_float4(0.f, 0.f, 0.f, 0.f);
        *(float4*)(sc + (size_t)t * 8 + 4) = make_float4(0.f, 0.f, 0.f, 0.f);
    }
}

// wave = (mt, a-half, b-chunk of 4). bfrag only 64 regs -> total ~140 regs,
// genuinely fits 3 waves/SIMD (512/3=170). DPP row-sum epilogue (no ds shfl).
// Two a-half waves combine via atomicAdd into pre-zeroed sc.
__global__ __launch_bounds__(256, 3)
void k1_scores(const _Float16* __restrict__ xh, const _Float16* __restrict__ wh,
               const unsigned short* __restrict__ ij,
               const float* __restrict__ wbg, const float* __restrict__ hg,
               float* __restrict__ sc)
{
    const int tid  = threadIdx.x;
    const int wid  = tid >> 6;
    const int lane = tid & 63;
    const int col  = lane & 15;
    const int quad = lane >> 4;
    const unsigned wave = blockIdx.x * 4u + wid;    // 0..25087
    const int mt   = wave % NMT;
    const unsigned rest = wave / NMT;               // 0..511
    const int nh   = rest & 1;                      // a-half
    const int b0   = (rest >> 1) * 4;               // 0..1020
    const int p0   = mt * 16;

    // B-fragments for this a-half: a = nh*64 + n*16 + col
    half8 bfrag[4][4];
#pragma unroll
    for (int n = 0; n < 4; ++n)
#pragma unroll
        for (int k = 0; k < 4; ++k)
            bfrag[n][k] = *(const half8*)(wh + (nh * 64 + n * 16 + col) * NE + k * 32 + quad * 8);

    float wbr[4], hr[4];
#pragma unroll
    for (int n = 0; n < 4; ++n) {
        wbr[n] = wbg[nh * 64 + n * 16 + col];
        hr[n]  = hg[nh * 64 + n * 16 + col];
    }

    const int v = ij[p0 + col];                     // fixed pair per lane
    const size_t roi = (size_t)((v >> 8) & 255) * NE + quad * 8;
    const size_t roj = (size_t)(v & 255) * NE + quad * 8;
    const _Float16* xb = xh + (size_t)b0 * XHB;

#pragma unroll
    for (int bi = 0; bi < 4; ++bi) {
        const _Float16* xp = xb + (size_t)bi * XHB;
        half8 af[4];
#pragma unroll
        for (int k = 0; k < 4; ++k) {
            half8 ai = *(const half8*)(xp + roi + k * 32);
            half8 aj = *(const half8*)(xp + roj + k * 32);
            af[k] = ai * aj;
        }

        floatx4 acc[4];
#pragma unroll
        for (int n = 0; n < 4; ++n) acc[n] = (floatx4){0.f, 0.f, 0.f, 0.f};
#pragma unroll
        for (int k = 0; k < 4; ++k)
#pragma unroll
            for (int n = 0; n < 4; ++n)
                acc[n] = __builtin_amdgcn_mfma_f32_16x16x32_f16(af[k], bfrag[n][k], acc[n], 0, 0, 0);

        // partial score for this a-half: sum_n relu(S+wb)*h, then 16-lane DPP row sum
        float ps[4];
#pragma unroll
        for (int r = 0; r < 4; ++r) {
            float s = 0.f;
#pragma unroll
            for (int n = 0; n < 4; ++n)
                s += fmaxf(acc[n][r] + wbr[n], 0.f) * hr[n];
            ps[r] = row16_sum(s);
        }
        if (col == 0) {
            float* scb = sc + (size_t)(b0 + bi) * NPT + p0 + quad * 4;
#pragma unroll
            for (int r = 0; r < 4; ++r)
                if (p0 + quad * 4 + r < NP) atomicAdd(&scb[r], ps[r]);
        }
    }
}

// Per-b tail: softmax, then out_un = sum_p exp_p * G[i,j], G = X diag(pw) X^T via MFMA.
__global__ __launch_bounds__(256, 4)
void k2_out(const _Float16* __restrict__ xh, const float* __restrict__ scg,
            const unsigned short* __restrict__ ijg, const _Float16* __restrict__ pwh,
            const float* __restrict__ pbg, float* __restrict__ out)
{
    __shared__ float G[48][49];             // 9408 B (+1 col pad)
    __shared__ float sc[NPT];               // 3136 B
    __shared__ unsigned short ij[NPT];      // 1568 B
    __shared__ float redm[4], reds[4], redo[4];

    const int tid  = threadIdx.x;
    const int wid  = tid >> 6;
    const int lane = tid & 63;
    const int b    = blockIdx.x;

    const float* scb = scg + (size_t)b * NPT;
    for (int p = tid; p < NPT; p += 256) {
        sc[p] = (p < NP) ? scb[p] : -1e30f;
        ij[p] = ijg[p];
    }
    __syncthreads();

    // softmax max
    float m = -1e30f;
    for (int p = tid; p < NP; p += 256) m = fmaxf(m, sc[p]);
#pragma unroll
    for (int off = 1; off < 64; off <<= 1) m = fmaxf(m, __shfl_xor(m, off));
    if (lane == 0) redm[wid] = m;
    __syncthreads();
    const float M = fmaxf(fmaxf(redm[0], redm[1]), fmaxf(redm[2], redm[3]));

    // exp + sum (unnormalized; 1/sum folded into final scalar)
    float s = 0.f;
    for (int p = tid; p < NP; p += 256) {
        float e = __expf(sc[p] - M);
        sc[p] = e;
        s += e;
    }
#pragma unroll
    for (int off = 1; off < 64; off <<= 1) s += __shfl_xor(s, off);
    if (lane == 0) reds[wid] = s;

    // G = X diag(pw) X^T : 3x3 padded 16x16 tiles, K=128, pw folded into B side
    const int col  = lane & 15;
    const int quad = lane >> 4;
    half8 pwf[4];
#pragma unroll
    for (int k = 0; k < 4; ++k)
        pwf[k] = *(const half8*)(pwh + k * 32 + quad * 8);
    const _Float16* xb = xh + (size_t)b * XHB;

    for (int t = wid; t < 9; t += 4) {
        const int mi = t / 3, ni = t % 3;
        const int row = mi * 16 + col;      // field i (A side)
        const int cln = ni * 16 + col;      // field j (B side)
        const bool rok = row < NF, cok = cln < NF;
        floatx4 acc = (floatx4){0.f, 0.f, 0.f, 0.f};
#pragma unroll
        for (int k = 0; k < 4; ++k) {
            half8 a = rok ? *(const half8*)(xb + row * NE + k * 32 + quad * 8) : (half8)(_Float16)0;
            half8 bb = cok ? (*(const half8*)(xb + cln * NE + k * 32 + quad * 8)) * pwf[k]
                           : (half8)(_Float16)0;
            acc = __builtin_amdgcn_mfma_f32_16x16x32_f16(a, bb, acc, 0, 0, 0);
        }
#pragma unroll
        for (int r = 0; r < 4; ++r)
            G[mi * 16 + quad * 4 + r][ni * 16 + col] = acc[r];
    }
    __syncthreads();   // sc(exp), reds, G all visible

    // out_un = sum_p exp_p * G[i,j]
    float g = 0.f;
    for (int p = tid; p < NP; p += 256) {
        int vv = ij[p];
        g += sc[p] * G[(vv >> 8) & 255][vv & 255];
    }
#pragma unroll
    for (int off = 1; off < 64; off <<= 1) g += __shfl_xor(g, off);
    if (lane == 0) redo[wid] = g;
    __syncthreads();
    if (tid == 0) {
        float S   = reds[0] + reds[1] + reds[2] + reds[3];
        float tot = redo[0] + redo[1] + redo[2] + redo[3];
        out[b] = tot / S + pbg[0];
    }
}

extern "C" void kernel_launch(void* const* d_in, const int* in_sizes, int n_in,
                              void* d_out, int out_size, void* d_ws, size_t ws_size,
                              hipStream_t stream) {
    const float* xg  = (const float*)d_in[0];  // x [1024,40,128]
    const float* wg  = (const float*)d_in[1];  // attn_w_w [128,128]
    const float* wbg = (const float*)d_in[2];  // attn_w_b [128]
    const float* hg  = (const float*)d_in[3];  // attn_h_w [1,128]
    // d_in[4] = attn_h_b : cancels in softmax
    const float* pwg = (const float*)d_in[5];  // attn_p_w [1,128]
    const float* pbg = (const float*)d_in[6];  // attn_p_b [1]

    char* ws = (char*)d_ws;
    _Float16* xh  = (_Float16*)(ws + OFF_XH);
    _Float16* wh  = (_Float16*)(ws + OFF_WH);
    unsigned short* ij = (unsigned short*)(ws + OFF_IJ);
    _Float16* pwh = (_Float16*)(ws + OFF_PW);
    float* sc     = (float*)(ws + OFF_SC);

    k0_prep<<<(T_END + 255) / 256, 256, 0, stream>>>(xg, wg, pwg, xh, wh, ij, pwh, sc);
    k1_scores<<<NB * NMT * 2 / 16, 256, 0, stream>>>(xh, wh, ij, wbg, hg, sc); // 6272 blocks
    k2_out<<<NB, 256, 0, stream>>>(xh, sc, ij, pwh, pbg, (float*)d_out);
}